// Round 3
// baseline (228.835 us; speedup 1.0000x reference)
//
#include <hip/hip_runtime.h>
#include <stdint.h>

// ---------------------------------------------------------------------------
// WideAndDeep: B=16384, F=3, C=256, D=64, H=1024, ND=13
// deep_in = 205 padded to 256. GEMMs: bf16 MFMA, 128x128 tile, BK=32,
// double-buffered LDS (load k+1 issued before compute of k).
// ---------------------------------------------------------------------------

#define BATCH 16384
#define HDIM 1024
#define KPAD 256
#define DEEP_IN 205

typedef short bf16x8 __attribute__((ext_vector_type(8)));
typedef float f32x4 __attribute__((ext_vector_type(4)));
typedef uint16_t u16x8 __attribute__((ext_vector_type(8)));

__device__ __forceinline__ float bf2f(uint16_t u) {
    uint32_t x = ((uint32_t)u) << 16;
    float f;
    __builtin_memcpy(&f, &x, 4);
    return f;
}

__device__ __forceinline__ uint16_t f2bf(float f) {
    uint32_t x;
    __builtin_memcpy(&x, &f, 4);
    uint32_t r = (x + 0x7fffu + ((x >> 16) & 1u)) >> 16;
    return (uint16_t)r;
}

__device__ __forceinline__ void async_ld16(const uint16_t* g, uint16_t* l) {
    __builtin_amdgcn_global_load_lds(
        (const __attribute__((address_space(1))) uint32_t*)g,
        (__attribute__((address_space(3))) uint32_t*)l, 16, 0, 0);
}

// ---------------------------------------------------------------------------
// Weight conversion, vectorized x8.
// W1 (1024x205 f32) -> W1b (1024x256 bf16, zero-padded K)
// W2 (1024x1024 f32) -> W2b bf16
// Grid: (1024*256/8 + 1024*1024/8) / 256 = (32768 + 131072)/256 = 640 blocks
// ---------------------------------------------------------------------------
__global__ __launch_bounds__(256) void convert_weights(
    const float* __restrict__ W1, const float* __restrict__ W2,
    uint16_t* __restrict__ W1b, uint16_t* __restrict__ W2b)
{
    int idx = blockIdx.x * 256 + threadIdx.x;
    if (idx < 32768) {               // W1: 8 elems per thread
        int n = idx >> 5, c0 = (idx & 31) * 8;
        u16x8 o;
#pragma unroll
        for (int t = 0; t < 8; t++) {
            int c = c0 + t;
            o[t] = (c < DEEP_IN) ? f2bf(W1[n * DEEP_IN + c]) : (uint16_t)0;
        }
        *(u16x8*)(W1b + (size_t)idx * 8) = o;
    } else {                         // W2: straight convert, 8 per thread
        int k = idx - 32768;         // < 131072
        const float* src = W2 + (size_t)k * 8;
        float4 v0 = *(const float4*)src;
        float4 v1 = *(const float4*)(src + 4);
        u16x8 o;
        o[0] = f2bf(v0.x); o[1] = f2bf(v0.y); o[2] = f2bf(v0.z); o[3] = f2bf(v0.w);
        o[4] = f2bf(v1.x); o[5] = f2bf(v1.y); o[6] = f2bf(v1.z); o[7] = f2bf(v1.w);
        *(u16x8*)(W2b + (size_t)k * 8) = o;
    }
}

// ---------------------------------------------------------------------------
// deep_x build, vectorized x8: [B][256] bf16 = concat(emb rows, dense, zeros)
// Grid: 16384*32/256 = 2048 blocks.
// ---------------------------------------------------------------------------
__global__ __launch_bounds__(256) void build_deepx(
    const int* __restrict__ sp, const float* __restrict__ dense,
    const float* __restrict__ emb, uint16_t* __restrict__ dx)
{
    int idx = blockIdx.x * 256 + threadIdx.x;  // < 16384*32
    int b = idx >> 5, c0 = (idx & 31) * 8;
    u16x8 o;
    if (c0 < 192) {
        int f = c0 >> 6, cc = c0 & 63;
        int s = sp[b * 3 + f];
        const float* e = emb + (size_t)(((f << 8) + s) * 64 + cc);
        float4 v0 = *(const float4*)e;
        float4 v1 = *(const float4*)(e + 4);
        o[0] = f2bf(v0.x); o[1] = f2bf(v0.y); o[2] = f2bf(v0.z); o[3] = f2bf(v0.w);
        o[4] = f2bf(v1.x); o[5] = f2bf(v1.y); o[6] = f2bf(v1.z); o[7] = f2bf(v1.w);
    } else {
#pragma unroll
        for (int t = 0; t < 8; t++) {
            int c = c0 + t;
            o[t] = (c >= 192 && c < DEEP_IN) ? f2bf(dense[b * 13 + (c - 192)])
                                             : (uint16_t)0;
        }
    }
    *(u16x8*)(dx + (size_t)idx * 8) = o;
}

// ---------------------------------------------------------------------------
// Wide path: exact fp32 gathers (replicates reference's cross = cross*F + s)
// ---------------------------------------------------------------------------
__global__ __launch_bounds__(256) void wide_kernel(
    const int* __restrict__ sp, const float* __restrict__ dense,
    const float* __restrict__ ww, const float* __restrict__ wb,
    float* __restrict__ wide)
{
    int b = blockIdx.x * 256 + threadIdx.x;  // < 16384
    int s0 = sp[b * 3], s1 = sp[b * 3 + 1], s2 = sp[b * 3 + 2];
    float w = wb[0];
    w += ww[s0] + ww[256 + s1] + ww[512 + s2];
    w += ww[768    + s0 * 3 + s1];
    w += ww[66304  + s0 * 3 + s2];
    w += ww[131840 + s1 * 3 + s2];
    w += ww[197376 + (s0 * 3 + s1) * 3 + s2];
    const float* wd = ww + 16974592;
    float acc = 0.f;
#pragma unroll
    for (int j = 0; j < 13; j++) acc += dense[b * 13 + j] * wd[j];
    wide[b] = w + acc;
}

// ---------------------------------------------------------------------------
// bf16 GEMM: C[M][N] = act(A[M][K] @ Bw[N][K]^T + bias[N])  (all row-major)
// 128x128 tile, BK=32, double-buffered LDS: stage tile k+1, compute tile k,
// then vmcnt(0)+barrier — load latency hides under the MFMA burst.
// Requires M%128==0, N==1024 (swizzle hardcodes nx=8), K%32==0, 16B-aligned.
// 1D grid (M/128)*8; XCD swizzle keeps one m-band's 8 n-blocks on one XCD.
// ---------------------------------------------------------------------------
__global__ __launch_bounds__(256) void gemm_bt(
    const uint16_t* __restrict__ A, const uint16_t* __restrict__ Bw,
    const float* __restrict__ bias, uint16_t* __restrict__ C,
    int M, int N, int K, int relu)
{
    __shared__ __align__(16) uint16_t Al[2][4096];  // 2 x 128x32 fragment order
    __shared__ __align__(16) uint16_t Bl[2][4096];

    const int tid = threadIdx.x;
    const int lane = tid & 63;
    const int wave = tid >> 6;
    const int wm = wave >> 1, wn = wave & 1;

    const int id = blockIdx.x;
    const int xcd = id & 7;
    const int slot = id >> 3;
    const int mb8 = (M >> 7) >> 3;
    const int by = xcd * mb8 + (slot >> 3);
    const int bx = slot & 7;
    const int bm = by * 128;
    const int bn = bx * 128;
    const int rl = lane & 15, q = lane >> 4;

    f32x4 acc[4][4];
#pragma unroll
    for (int i = 0; i < 4; i++)
#pragma unroll
        for (int j = 0; j < 4; j++) acc[i][j] = (f32x4)0.f;

    // Staging (fragment order): chunk c = 16 rows x 32 k = 1 KB, one
    // global_load_lds(16B) per wave per chunk; wave w stages chunks 2w,2w+1
    // of A and B. Lane l lands at chunk_base + l*16B = row l&15, k (l>>4)*8.
    const int c0 = wave * 2, c1 = wave * 2 + 1;
    const uint16_t* aS0 = A + (size_t)(bm + c0 * 16 + rl) * K + q * 8;
    const uint16_t* aS1 = A + (size_t)(bm + c1 * 16 + rl) * K + q * 8;
    const uint16_t* bS0 = Bw + (size_t)(bn + c0 * 16 + rl) * K + q * 8;
    const uint16_t* bS1 = Bw + (size_t)(bn + c1 * 16 + rl) * K + q * 8;
    const int dA0 = c0 * 512, dA1 = c1 * 512;

    // Prologue: tile 0 -> buffer 0
    async_ld16(aS0, &Al[0][dA0]);
    async_ld16(aS1, &Al[0][dA1]);
    async_ld16(bS0, &Bl[0][dA0]);
    async_ld16(bS1, &Bl[0][dA1]);
    asm volatile("s_waitcnt vmcnt(0)" ::: "memory");
    __syncthreads();

    int p = 0;
    for (int k0 = 32; k0 < K; k0 += 32) {
        // issue next tile's loads into the other buffer (no wait)
        async_ld16(aS0 + k0, &Al[p ^ 1][dA0]);
        async_ld16(aS1 + k0, &Al[p ^ 1][dA1]);
        async_ld16(bS0 + k0, &Bl[p ^ 1][dA0]);
        async_ld16(bS1 + k0, &Bl[p ^ 1][dA1]);

        // compute current buffer
        bf16x8 af[4], bfr[4];
#pragma unroll
        for (int i = 0; i < 4; i++)
            af[i] = *(const bf16x8*)&Al[p][(wm * 4 + i) * 512 + lane * 8];
#pragma unroll
        for (int j = 0; j < 4; j++)
            bfr[j] = *(const bf16x8*)&Bl[p][(wn * 4 + j) * 512 + lane * 8];
#pragma unroll
        for (int i = 0; i < 4; i++)
#pragma unroll
            for (int j = 0; j < 4; j++)
                acc[i][j] = __builtin_amdgcn_mfma_f32_16x16x32_bf16(
                    af[i], bfr[j], acc[i][j], 0, 0, 0);

        asm volatile("s_waitcnt vmcnt(0)" ::: "memory");
        __syncthreads();
        p ^= 1;
    }

    // last tile
    {
        bf16x8 af[4], bfr[4];
#pragma unroll
        for (int i = 0; i < 4; i++)
            af[i] = *(const bf16x8*)&Al[p][(wm * 4 + i) * 512 + lane * 8];
#pragma unroll
        for (int j = 0; j < 4; j++)
            bfr[j] = *(const bf16x8*)&Bl[p][(wn * 4 + j) * 512 + lane * 8];
#pragma unroll
        for (int i = 0; i < 4; i++)
#pragma unroll
            for (int j = 0; j < 4; j++)
                acc[i][j] = __builtin_amdgcn_mfma_f32_16x16x32_bf16(
                    af[i], bfr[j], acc[i][j], 0, 0, 0);
    }

    // Epilogue: C/D layout col = lane&15, row = (lane>>4)*4 + reg
#pragma unroll
    for (int i = 0; i < 4; i++) {
#pragma unroll
        for (int j = 0; j < 4; j++) {
            int n = bn + (wn * 4 + j) * 16 + rl;
            float bv = bias[n];
#pragma unroll
            for (int r = 0; r < 4; r++) {
                int m = bm + (wm * 4 + i) * 16 + q * 4 + r;
                float v = acc[i][j][r] + bv;
                if (relu) v = fmaxf(v, 0.f);
                C[(size_t)m * N + n] = f2bf(v);
            }
        }
    }
}

// ---------------------------------------------------------------------------
// Final: out[b] = sigmoid(wide[b] + h2[b] . W3 + b3); one wave per row.
// ---------------------------------------------------------------------------
__global__ __launch_bounds__(256) void final_kernel(
    const uint16_t* __restrict__ h2, const float* __restrict__ W3,
    const float* __restrict__ b3, const float* __restrict__ wide,
    float* __restrict__ out)
{
    int wave = threadIdx.x >> 6, lane = threadIdx.x & 63;
    int row = blockIdx.x * 4 + wave;  // grid 4096
    const uint16_t* hr = h2 + (size_t)row * HDIM + lane * 16;
    u16x8 h0 = *(const u16x8*)hr;
    u16x8 h1 = *(const u16x8*)(hr + 8);
    const float* w3 = W3 + lane * 16;
    float s = 0.f;
#pragma unroll
    for (int t = 0; t < 8; t++) s += bf2f(h0[t]) * w3[t];
#pragma unroll
    for (int t = 0; t < 8; t++) s += bf2f(h1[t]) * w3[8 + t];
#pragma unroll
    for (int off = 32; off; off >>= 1) s += __shfl_down(s, off, 64);
    if (lane == 0) {
        float x = s + wide[row] + b3[0];
        out[row] = 1.f / (1.f + __expf(-x));
    }
}

// ---------------------------------------------------------------------------
extern "C" void kernel_launch(void* const* d_in, const int* in_sizes, int n_in,
                              void* d_out, int out_size, void* d_ws, size_t ws_size,
                              hipStream_t stream) {
    const int*   sp    = (const int*)d_in[0];
    const float* dense = (const float*)d_in[1];
    const float* ww    = (const float*)d_in[2];
    const float* wb    = (const float*)d_in[3];
    const float* emb   = (const float*)d_in[4];
    const float* W1    = (const float*)d_in[5];
    const float* b1    = (const float*)d_in[6];
    const float* W2    = (const float*)d_in[7];
    const float* b2    = (const float*)d_in[8];
    const float* W3    = (const float*)d_in[9];
    const float* b3    = (const float*)d_in[10];
    float* out = (float*)d_out;

    char* ws = (char*)d_ws;
    float*    wide = (float*)ws;                       //     65,536 B
    uint16_t* dxp  = (uint16_t*)(ws + 65536);          //  8,388,608 B
    uint16_t* W1b  = (uint16_t*)(ws + 8454144);        //    524,288 B
    uint16_t* W2b  = (uint16_t*)(ws + 8978432);        //  2,097,152 B
    uint16_t* h1   = (uint16_t*)(ws + 11075584);       // 33,554,432 B
    uint16_t* h2   = (uint16_t*)(ws + 44630016);       // 33,554,432 B -> 78,184,448 total

    convert_weights<<<640, 256, 0, stream>>>(W1, W2, W1b, W2b);
    build_deepx<<<2048, 256, 0, stream>>>(sp, dense, emb, dxp);
    wide_kernel<<<64, 256, 0, stream>>>(sp, dense, ww, wb, wide);
    gemm_bt<<<(BATCH / 128) * 8, 256, 0, stream>>>(
        dxp, W1b, b1, h1, BATCH, HDIM, KPAD, 1);
    gemm_bt<<<(BATCH / 128) * 8, 256, 0, stream>>>(
        h1, W2b, b2, h2, BATCH, HDIM, HDIM, 1);
    final_kernel<<<BATCH / 4, 256, 0, stream>>>(h2, W3, b3, wide, out);
}

// Round 4
// 217.961 us; speedup vs baseline: 1.0499x; 1.0499x over previous
//
#include <hip/hip_runtime.h>
#include <stdint.h>

// ---------------------------------------------------------------------------
// WideAndDeep: B=16384, F=3, C=256, D=64, H=1024, ND=13
// deep_in = 205 padded to 256. GEMMs: bf16 MFMA, 128x128 block tile,
// 8 waves x (64x32 acc = 32 AGPR) to double occupancy vs 4-wave/64-AGPR,
// BK=32, double-buffered LDS.
// ---------------------------------------------------------------------------

#define BATCH 16384
#define HDIM 1024
#define KPAD 256
#define DEEP_IN 205

typedef short bf16x8 __attribute__((ext_vector_type(8)));
typedef float f32x4 __attribute__((ext_vector_type(4)));
typedef uint16_t u16x8 __attribute__((ext_vector_type(8)));

__device__ __forceinline__ float bf2f(uint16_t u) {
    uint32_t x = ((uint32_t)u) << 16;
    float f;
    __builtin_memcpy(&f, &x, 4);
    return f;
}

__device__ __forceinline__ uint16_t f2bf(float f) {
    uint32_t x;
    __builtin_memcpy(&x, &f, 4);
    uint32_t r = (x + 0x7fffu + ((x >> 16) & 1u)) >> 16;
    return (uint16_t)r;
}

__device__ __forceinline__ void async_ld16(const uint16_t* g, uint16_t* l) {
    __builtin_amdgcn_global_load_lds(
        (const __attribute__((address_space(1))) uint32_t*)g,
        (__attribute__((address_space(3))) uint32_t*)l, 16, 0, 0);
}

// ---------------------------------------------------------------------------
// Fused prep (one launch instead of three):
//   blocks [0, 2048)      : build deep_x  [B][256] bf16  (x8 vectorized)
//   blocks [2048, 2560)   : W2 -> bf16               (x8 vectorized)
//   blocks [2560, 2688)   : W1 -> bf16 K-padded      (x8 vectorized)
//   blocks [2688, 2752)   : wide path (fp32 gathers)
// ---------------------------------------------------------------------------
__global__ __launch_bounds__(256) void prep_kernel(
    const int* __restrict__ sp, const float* __restrict__ dense,
    const float* __restrict__ emb,
    const float* __restrict__ W1, const float* __restrict__ W2,
    const float* __restrict__ ww, const float* __restrict__ wb,
    uint16_t* __restrict__ dx, uint16_t* __restrict__ W1b,
    uint16_t* __restrict__ W2b, float* __restrict__ wide)
{
    const int bid = blockIdx.x;
    if (bid < 2048) {                      // ---- deep_x build
        int idx = bid * 256 + threadIdx.x; // < 16384*32
        int b = idx >> 5, c0 = (idx & 31) * 8;
        u16x8 o;
        if (c0 < 192) {
            int f = c0 >> 6, cc = c0 & 63;
            int s = sp[b * 3 + f];
            const float* e = emb + (size_t)(((f << 8) + s) * 64 + cc);
            float4 v0 = *(const float4*)e;
            float4 v1 = *(const float4*)(e + 4);
            o[0] = f2bf(v0.x); o[1] = f2bf(v0.y); o[2] = f2bf(v0.z); o[3] = f2bf(v0.w);
            o[4] = f2bf(v1.x); o[5] = f2bf(v1.y); o[6] = f2bf(v1.z); o[7] = f2bf(v1.w);
        } else {
#pragma unroll
            for (int t = 0; t < 8; t++) {
                int c = c0 + t;
                o[t] = (c >= 192 && c < DEEP_IN) ? f2bf(dense[b * 13 + (c - 192)])
                                                 : (uint16_t)0;
            }
        }
        *(u16x8*)(dx + (size_t)idx * 8) = o;
    } else if (bid < 2560) {               // ---- W2 convert
        int k = (bid - 2048) * 256 + threadIdx.x;  // < 131072
        const float* src = W2 + (size_t)k * 8;
        float4 v0 = *(const float4*)src;
        float4 v1 = *(const float4*)(src + 4);
        u16x8 o;
        o[0] = f2bf(v0.x); o[1] = f2bf(v0.y); o[2] = f2bf(v0.z); o[3] = f2bf(v0.w);
        o[4] = f2bf(v1.x); o[5] = f2bf(v1.y); o[6] = f2bf(v1.z); o[7] = f2bf(v1.w);
        *(u16x8*)(W2b + (size_t)k * 8) = o;
    } else if (bid < 2688) {               // ---- W1 convert, pad 205->256
        int idx = (bid - 2560) * 256 + threadIdx.x;  // < 32768
        int n = idx >> 5, c0 = (idx & 31) * 8;
        u16x8 o;
#pragma unroll
        for (int t = 0; t < 8; t++) {
            int c = c0 + t;
            o[t] = (c < DEEP_IN) ? f2bf(W1[n * DEEP_IN + c]) : (uint16_t)0;
        }
        *(u16x8*)(W1b + (size_t)idx * 8) = o;
    } else {                               // ---- wide path
        int b = (bid - 2688) * 256 + threadIdx.x;  // < 16384
        int s0 = sp[b * 3], s1 = sp[b * 3 + 1], s2 = sp[b * 3 + 2];
        float w = wb[0];
        w += ww[s0] + ww[256 + s1] + ww[512 + s2];
        w += ww[768    + s0 * 3 + s1];
        w += ww[66304  + s0 * 3 + s2];
        w += ww[131840 + s1 * 3 + s2];
        w += ww[197376 + (s0 * 3 + s1) * 3 + s2];
        const float* wd = ww + 16974592;
        float acc = 0.f;
#pragma unroll
        for (int j = 0; j < 13; j++) acc += dense[b * 13 + j] * wd[j];
        wide[b] = w + acc;
    }
}

// ---------------------------------------------------------------------------
// bf16 GEMM: C[M][N] = act(A[M][K] @ Bw[N][K]^T + bias[N])  (all row-major)
// 128x128 tile, 512 threads = 8 waves arranged 2(m) x 4(n); each wave owns a
// 64x32 output (4x2 16x16 frags = 32 AGPR) so regs/wave ~= 100 -> 16 waves/CU
// (vs 136 regs -> 8 waves/CU with the 4-wave/64-AGPR layout).
// BK=32 double-buffered LDS; global_load_lds(16B); fragment-order LDS.
// Requires M%128==0, N==1024 (swizzle hardcodes nx=8), K%32==0, 16B-aligned.
// 1D grid (M/128)*8; XCD swizzle keeps one m-band's 8 n-blocks on one XCD.
// ---------------------------------------------------------------------------
__global__ __launch_bounds__(512) void gemm_bt(
    const uint16_t* __restrict__ A, const uint16_t* __restrict__ Bw,
    const float* __restrict__ bias, uint16_t* __restrict__ C,
    int M, int N, int K, int relu)
{
    __shared__ __align__(16) uint16_t Al[2][4096];  // 2 x (128 rows x 32 k)
    __shared__ __align__(16) uint16_t Bl[2][4096];

    const int tid = threadIdx.x;
    const int lane = tid & 63;
    const int wave = tid >> 6;   // 0..7
    const int wm = wave >> 2;    // 0..1 : m-half (64 rows)
    const int wn = wave & 3;     // 0..3 : n-quarter (32 cols)

    const int id = blockIdx.x;
    const int xcd = id & 7;
    const int slot = id >> 3;
    const int mb8 = (M >> 7) >> 3;
    const int by = xcd * mb8 + (slot >> 3);
    const int bx = slot & 7;
    const int bm = by * 128;
    const int bn = bx * 128;
    const int rl = lane & 15, q = lane >> 4;

    f32x4 acc[4][2];
#pragma unroll
    for (int i = 0; i < 4; i++)
#pragma unroll
        for (int j = 0; j < 2; j++) acc[i][j] = (f32x4)0.f;

    // Staging (fragment order): chunk c = 16 rows x 32 k = 1 KB. Wave w
    // stages chunk w of A and chunk w of B (one async_ld16 each).
    // Lane l lands at chunk_base + l*16B = row l&15, k (l>>4)*8.
    const uint16_t* aS = A + (size_t)(bm + wave * 16 + rl) * K + q * 8;
    const uint16_t* bS = Bw + (size_t)(bn + wave * 16 + rl) * K + q * 8;
    const int dOf = wave * 512;

    // Prologue: tile 0 -> buffer 0
    async_ld16(aS, &Al[0][dOf]);
    async_ld16(bS, &Bl[0][dOf]);
    asm volatile("s_waitcnt vmcnt(0)" ::: "memory");
    __syncthreads();

    int p = 0;
    for (int k0 = 32; k0 < K; k0 += 32) {
        // issue next tile's loads into the other buffer (no wait)
        async_ld16(aS + k0, &Al[p ^ 1][dOf]);
        async_ld16(bS + k0, &Bl[p ^ 1][dOf]);

        // compute current buffer
        bf16x8 af[4], bfr[2];
#pragma unroll
        for (int i = 0; i < 4; i++)
            af[i] = *(const bf16x8*)&Al[p][(wm * 4 + i) * 512 + lane * 8];
#pragma unroll
        for (int j = 0; j < 2; j++)
            bfr[j] = *(const bf16x8*)&Bl[p][(wn * 2 + j) * 512 + lane * 8];
#pragma unroll
        for (int i = 0; i < 4; i++)
#pragma unroll
            for (int j = 0; j < 2; j++)
                acc[i][j] = __builtin_amdgcn_mfma_f32_16x16x32_bf16(
                    af[i], bfr[j], acc[i][j], 0, 0, 0);

        asm volatile("s_waitcnt vmcnt(0)" ::: "memory");
        __syncthreads();
        p ^= 1;
    }

    // last tile
    {
        bf16x8 af[4], bfr[2];
#pragma unroll
        for (int i = 0; i < 4; i++)
            af[i] = *(const bf16x8*)&Al[p][(wm * 4 + i) * 512 + lane * 8];
#pragma unroll
        for (int j = 0; j < 2; j++)
            bfr[j] = *(const bf16x8*)&Bl[p][(wn * 2 + j) * 512 + lane * 8];
#pragma unroll
        for (int i = 0; i < 4; i++)
#pragma unroll
            for (int j = 0; j < 2; j++)
                acc[i][j] = __builtin_amdgcn_mfma_f32_16x16x32_bf16(
                    af[i], bfr[j], acc[i][j], 0, 0, 0);
    }

    // Epilogue: C/D layout col = lane&15, row = (lane>>4)*4 + reg
#pragma unroll
    for (int i = 0; i < 4; i++) {
#pragma unroll
        for (int j = 0; j < 2; j++) {
            int n = bn + (wn * 2 + j) * 16 + rl;
            float bv = bias[n];
#pragma unroll
            for (int r = 0; r < 4; r++) {
                int m = bm + (wm * 4 + i) * 16 + q * 4 + r;
                float v = acc[i][j][r] + bv;
                if (relu) v = fmaxf(v, 0.f);
                C[(size_t)m * N + n] = f2bf(v);
            }
        }
    }
}

// ---------------------------------------------------------------------------
// Final: out[b] = sigmoid(wide[b] + h2[b] . W3 + b3); one wave per row.
// ---------------------------------------------------------------------------
__global__ __launch_bounds__(256) void final_kernel(
    const uint16_t* __restrict__ h2, const float* __restrict__ W3,
    const float* __restrict__ b3, const float* __restrict__ wide,
    float* __restrict__ out)
{
    int wave = threadIdx.x >> 6, lane = threadIdx.x & 63;
    int row = blockIdx.x * 4 + wave;  // grid 4096
    const uint16_t* hr = h2 + (size_t)row * HDIM + lane * 16;
    u16x8 h0 = *(const u16x8*)hr;
    u16x8 h1 = *(const u16x8*)(hr + 8);
    const float* w3 = W3 + lane * 16;
    float s = 0.f;
#pragma unroll
    for (int t = 0; t < 8; t++) s += bf2f(h0[t]) * w3[t];
#pragma unroll
    for (int t = 0; t < 8; t++) s += bf2f(h1[t]) * w3[8 + t];
#pragma unroll
    for (int off = 32; off; off >>= 1) s += __shfl_down(s, off, 64);
    if (lane == 0) {
        float x = s + wide[row] + b3[0];
        out[row] = 1.f / (1.f + __expf(-x));
    }
}

// ---------------------------------------------------------------------------
extern "C" void kernel_launch(void* const* d_in, const int* in_sizes, int n_in,
                              void* d_out, int out_size, void* d_ws, size_t ws_size,
                              hipStream_t stream) {
    const int*   sp    = (const int*)d_in[0];
    const float* dense = (const float*)d_in[1];
    const float* ww    = (const float*)d_in[2];
    const float* wb    = (const float*)d_in[3];
    const float* emb   = (const float*)d_in[4];
    const float* W1    = (const float*)d_in[5];
    const float* b1    = (const float*)d_in[6];
    const float* W2    = (const float*)d_in[7];
    const float* b2    = (const float*)d_in[8];
    const float* W3    = (const float*)d_in[9];
    const float* b3    = (const float*)d_in[10];
    float* out = (float*)d_out;

    char* ws = (char*)d_ws;
    float*    wide = (float*)ws;                       //     65,536 B
    uint16_t* dxp  = (uint16_t*)(ws + 65536);          //  8,388,608 B
    uint16_t* W1b  = (uint16_t*)(ws + 8454144);        //    524,288 B
    uint16_t* W2b  = (uint16_t*)(ws + 8978432);        //  2,097,152 B
    uint16_t* h1   = (uint16_t*)(ws + 11075584);       // 33,554,432 B
    uint16_t* h2   = (uint16_t*)(ws + 44630016);       // 33,554,432 B -> 78,184,448 total

    prep_kernel<<<2752, 256, 0, stream>>>(sp, dense, emb, W1, W2, ww, wb,
                                          dxp, W1b, W2b, wide);
    gemm_bt<<<(BATCH / 128) * 8, 512, 0, stream>>>(
        dxp, W1b, b1, h1, BATCH, HDIM, KPAD, 1);
    gemm_bt<<<(BATCH / 128) * 8, 512, 0, stream>>>(
        h1, W2b, b2, h2, BATCH, HDIM, HDIM, 1);
    final_kernel<<<BATCH / 4, 256, 0, stream>>>(h2, W3, b3, wide, out);
}